// Round 1
// baseline (1672.698 us; speedup 1.0000x reference)
//
#include <hip/hip_runtime.h>
#include <math.h>

#define NN 100000
#define NE 1000000
#define DH 64
#define DIN 128
#define DOUT 40
#define NL 7

__device__ __forceinline__ float lane_bcast(float v, int l) {
  return __int_as_float(__builtin_amdgcn_readlane(__float_as_int(v), l));
}

// ---------------- CSR build ----------------
__global__ __launch_bounds__(256) void k_count(const int* __restrict__ dst,
                                               int* __restrict__ cnt) {
  int i = blockIdx.x * 256 + threadIdx.x;
  if (i < NE) atomicAdd(&cnt[dst[i]], 1);
}

__global__ __launch_bounds__(1024) void k_scan(const int* __restrict__ cnt,
                                               int* __restrict__ row_ptr,
                                               int* __restrict__ cur) {
  __shared__ int buf[1024];
  __shared__ int carry_s;
  int tid = threadIdx.x;
  if (tid == 0) carry_s = 0;
  __syncthreads();
  for (int base = 0; base < NN; base += 1024) {
    int i = base + tid;
    int v = (i < NN) ? cnt[i] : 0;
    buf[tid] = v;
    __syncthreads();
    for (int off = 1; off < 1024; off <<= 1) {
      int t = (tid >= off) ? buf[tid - off] : 0;
      __syncthreads();
      buf[tid] += t;
      __syncthreads();
    }
    int carry = carry_s;
    int excl = buf[tid] - v;
    if (i < NN) { int rp = carry + excl; row_ptr[i] = rp; cur[i] = rp; }
    __syncthreads();
    if (tid == 1023) carry_s = carry + buf[1023];
    __syncthreads();
  }
  if (tid == 0) row_ptr[NN] = carry_s;
}

__global__ __launch_bounds__(256) void k_scatter(const int* __restrict__ src,
                                                 const int* __restrict__ dst,
                                                 int* __restrict__ cur,
                                                 int* __restrict__ col) {
  int i = blockIdx.x * 256 + threadIdx.x;
  if (i < NE) {
    int d = dst[i];
    int p = atomicAdd(&cur[d], 1);
    col[p] = src[i];
  }
}

// ---------------- Encoder: h = x @ W_enc + b_enc ----------------
__global__ __launch_bounds__(256) void k_encoder(const float* __restrict__ x,
                                                 const float* __restrict__ W,
                                                 const float* __restrict__ b,
                                                 float* __restrict__ h) {
  int lane = threadIdx.x & 63;
  float wc[DIN];
#pragma unroll
  for (int k = 0; k < DIN; ++k) wc[k] = W[k * DH + lane];
  float bj = b[lane];
  int wid = (blockIdx.x * blockDim.x + threadIdx.x) >> 6;
  int nw = (gridDim.x * blockDim.x) >> 6;
  for (int n = wid; n < NN; n += nw) {
    float v0 = x[n * DIN + lane];
    float v1 = x[n * DIN + 64 + lane];
    float acc = bj;
#pragma unroll
    for (int k = 0; k < 64; ++k) acc += lane_bcast(v0, k) * wc[k];
#pragma unroll
    for (int k = 0; k < 64; ++k) acc += lane_bcast(v1, k) * wc[64 + k];
    h[n * DH + lane] = acc;
  }
}

// ---------------- BN stats: col sums and sumsq ----------------
__global__ __launch_bounds__(256) void k_bnstats(const float* __restrict__ h,
                                                 float* __restrict__ stats) {
  int f = threadIdx.x & 63;
  int rg = threadIdx.x >> 6;  // 0..3
  float s = 0.f, q = 0.f;
  for (int n = blockIdx.x * 4 + rg; n < NN; n += gridDim.x * 4) {
    float v = h[n * DH + f];
    s += v;
    q += v * v;
  }
  __shared__ float ls[256], lq[256];
  ls[threadIdx.x] = s;
  lq[threadIdx.x] = q;
  __syncthreads();
  if (threadIdx.x < 64) {
    s = ls[f] + ls[f + 64] + ls[f + 128] + ls[f + 192];
    q = lq[f] + lq[f + 64] + lq[f + 128] + lq[f + 192];
    atomicAdd(&stats[f], s);
    atomicAdd(&stats[64 + f], q);
  }
}

// ---------------- BN apply + ReLU ----------------
__global__ __launch_bounds__(256) void k_bnapply(const float* __restrict__ h,
                                                 const float* __restrict__ stats,
                                                 const float* __restrict__ gamma,
                                                 const float* __restrict__ beta,
                                                 float* __restrict__ h2) {
  int i = blockIdx.x * 256 + threadIdx.x;
  if (i >= NN * DH) return;
  int f = i & 63;
  const float inv_n = 1.0f / (float)NN;
  float mu = stats[f] * inv_n;
  float var = stats[64 + f] * inv_n - mu * mu;
  float g = gamma[f] * rsqrtf(var + 1e-5f);
  float v = (h[i] - mu) * g + beta[f];
  h2[i] = fmaxf(v, 0.f);
}

// ---------------- GENConv aggregation: online segment softmax ----------------
__global__ __launch_bounds__(256) void k_aggregate(const float* __restrict__ hin,
                                                   const int* __restrict__ row_ptr,
                                                   const int* __restrict__ col,
                                                   float* __restrict__ agg) {
  int lane = threadIdx.x & 63;
  int wid = (blockIdx.x * blockDim.x + threadIdx.x) >> 6;
  int nw = (gridDim.x * blockDim.x) >> 6;
  for (int n = wid; n < NN; n += nw) {
    int beg = row_ptr[n], end = row_ptr[n + 1];
    float m = -INFINITY, s = 0.f, t = 0.f;
    for (int j = beg; j < end; ++j) {
      int sc = col[j];  // wave-uniform -> scalar load
      float v = fmaxf(hin[sc * DH + lane], 0.f) + 1e-7f;
      float nm = fmaxf(m, v);
      float scale = __expf(m - nm);   // first iter: exp(-inf) = 0
      float e = __expf(v - nm);
      s = s * scale + e;
      t = t * scale + e * v;
      m = nm;
    }
    agg[n * DH + lane] = t / (s + 1e-16f);
  }
}

// ---------------- 64x64 GEMM: hout = (hin+agg)@W + b (+res) ----------------
__global__ __launch_bounds__(256) void k_gemm64(const float* __restrict__ hin,
                                                const float* __restrict__ agg,
                                                const float* __restrict__ W,
                                                const float* __restrict__ b,
                                                const float* __restrict__ res,
                                                float* __restrict__ hout) {
  int lane = threadIdx.x & 63;
  float wc[DH];
#pragma unroll
  for (int k = 0; k < DH; ++k) wc[k] = W[k * DH + lane];
  float bj = b[lane];
  int wid = (blockIdx.x * blockDim.x + threadIdx.x) >> 6;
  int nw = (gridDim.x * blockDim.x) >> 6;
  for (int n = wid; n < NN; n += nw) {
    float v = hin[n * DH + lane] + agg[n * DH + lane];
    float acc = bj;
#pragma unroll
    for (int k = 0; k < DH; ++k) acc += lane_bcast(v, k) * wc[k];
    if (res) acc += res[n * DH + lane];
    hout[n * DH + lane] = acc;
  }
}

// ---------------- Prediction head + log_softmax ----------------
__global__ __launch_bounds__(256) void k_pred(const float* __restrict__ hin,
                                              const float* __restrict__ Wp,
                                              const float* __restrict__ bp,
                                              float* __restrict__ out) {
  int lane = threadIdx.x & 63;
  int lc = lane < DOUT ? lane : DOUT - 1;
  float wc[DH];
#pragma unroll
  for (int k = 0; k < DH; ++k) wc[k] = Wp[k * DOUT + lc];
  float bj = bp[lc];
  int wid = (blockIdx.x * blockDim.x + threadIdx.x) >> 6;
  int nw = (gridDim.x * blockDim.x) >> 6;
  for (int n = wid; n < NN; n += nw) {
    float v = hin[n * DH + lane];
    float acc = bj;
#pragma unroll
    for (int k = 0; k < DH; ++k) acc += lane_bcast(v, k) * wc[k];
    float xm = (lane < DOUT) ? acc : -INFINITY;
#pragma unroll
    for (int o = 32; o >= 1; o >>= 1) xm = fmaxf(xm, __shfl_xor(xm, o, 64));
    float e = (lane < DOUT) ? __expf(acc - xm) : 0.f;
#pragma unroll
    for (int o = 32; o >= 1; o >>= 1) e += __shfl_xor(e, o, 64);
    if (lane < DOUT) out[n * DOUT + lane] = acc - xm - __logf(e);
  }
}

extern "C" void kernel_launch(void* const* d_in, const int* in_sizes, int n_in,
                              void* d_out, int out_size, void* d_ws, size_t ws_size,
                              hipStream_t stream) {
  const float* x      = (const float*)d_in[0];
  const int*   ei     = (const int*)d_in[1];
  const float* W_enc  = (const float*)d_in[2];
  const float* b_enc  = (const float*)d_in[3];
  const float* Wg     = (const float*)d_in[4];
  const float* bg     = (const float*)d_in[5];
  const float* gamma  = (const float*)d_in[6];
  const float* beta   = (const float*)d_in[7];
  const float* W_pred = (const float*)d_in[8];
  const float* b_pred = (const float*)d_in[9];
  float* out = (float*)d_out;

  const int* src = ei;
  const int* dst = ei + NE;

  char* p = (char*)d_ws;
  auto alloc = [&](size_t bytes) -> void* {
    void* r = (void*)p;
    p += (bytes + 255) & ~(size_t)255;
    return r;
  };
  float* hA      = (float*)alloc((size_t)NN * DH * 4);
  float* hB      = (float*)alloc((size_t)NN * DH * 4);
  float* h2      = (float*)alloc((size_t)NN * DH * 4);
  float* agg     = (float*)alloc((size_t)NN * DH * 4);
  int*   row_ptr = (int*)alloc((size_t)(NN + 1) * 4);
  int*   cur     = (int*)alloc((size_t)NN * 4);
  int*   cnt     = (int*)alloc((size_t)NN * 4);
  int*   col     = (int*)alloc((size_t)NE * 4);
  float* stats   = (float*)alloc(128 * 4);

  // ---- CSR build ----
  hipMemsetAsync(cnt, 0, (size_t)NN * 4, stream);
  k_count<<<(NE + 255) / 256, 256, 0, stream>>>(dst, cnt);
  k_scan<<<1, 1024, 0, stream>>>(cnt, row_ptr, cur);
  k_scatter<<<(NE + 255) / 256, 256, 0, stream>>>(src, dst, cur, col);

  // ---- Encoder ----
  k_encoder<<<1024, 256, 0, stream>>>(x, W_enc, b_enc, hA);

  const int AGG_BLOCKS = 2048;
  const int GEMM_BLOCKS = 1024;

  // ---- Layer 0: h = (h + agg)@Wg0 + bg0 ----
  k_aggregate<<<AGG_BLOCKS, 256, 0, stream>>>(hA, row_ptr, col, agg);
  k_gemm64<<<GEMM_BLOCKS, 256, 0, stream>>>(hA, agg, Wg, bg, nullptr, hB);

  float* h = hB;
  float* hn = hA;
  for (int l = 1; l < NL; ++l) {
    hipMemsetAsync(stats, 0, 512, stream);
    k_bnstats<<<1024, 256, 0, stream>>>(h, stats);
    k_bnapply<<<(NN * DH + 255) / 256, 256, 0, stream>>>(
        h, stats, gamma + (size_t)(l - 1) * DH, beta + (size_t)(l - 1) * DH, h2);
    k_aggregate<<<AGG_BLOCKS, 256, 0, stream>>>(h2, row_ptr, col, agg);
    k_gemm64<<<GEMM_BLOCKS, 256, 0, stream>>>(
        h2, agg, Wg + (size_t)l * DH * DH, bg + (size_t)l * DH, h, hn);
    float* tmp = h; h = hn; hn = tmp;
  }

  // ---- Final BN + ReLU + prediction + log_softmax ----
  hipMemsetAsync(stats, 0, 512, stream);
  k_bnstats<<<1024, 256, 0, stream>>>(h, stats);
  k_bnapply<<<(NN * DH + 255) / 256, 256, 0, stream>>>(
      h, stats, gamma + (size_t)(NL - 1) * DH, beta + (size_t)(NL - 1) * DH, h2);
  k_pred<<<GEMM_BLOCKS, 256, 0, stream>>>(h2, W_pred, b_pred, out);
}

// Round 4
// 1025.155 us; speedup vs baseline: 1.6317x; 1.6317x over previous
//
#include <hip/hip_runtime.h>
#include <math.h>

#define NN 100000
#define NE 1000000
#define DH 64
#define DIN 128
#define DOUT 40
#define NL 7
#define SCAN_B 1024
#define NBLK ((NN + SCAN_B - 1) / SCAN_B)  // 98

__device__ __forceinline__ float lane_bcast(float v, int l) {
  return __int_as_float(__builtin_amdgcn_readlane(__float_as_int(v), l));
}

// ---------------- CSR build ----------------
__global__ __launch_bounds__(256) void k_count(const int* __restrict__ dst,
                                               int* __restrict__ cnt) {
  int i = blockIdx.x * 256 + threadIdx.x;
  if (i < NE) atomicAdd(&cnt[dst[i]], 1);
}

// per-block exclusive scan + block totals
__global__ __launch_bounds__(SCAN_B) void k_scan1(const int* __restrict__ cnt,
                                                  int* __restrict__ row_ptr,
                                                  int* __restrict__ bsum) {
  __shared__ int buf[SCAN_B];
  int i = blockIdx.x * SCAN_B + threadIdx.x;
  int v = (i < NN) ? cnt[i] : 0;
  buf[threadIdx.x] = v;
  __syncthreads();
  for (int off = 1; off < SCAN_B; off <<= 1) {
    int t = (threadIdx.x >= off) ? buf[threadIdx.x - off] : 0;
    __syncthreads();
    buf[threadIdx.x] += t;
    __syncthreads();
  }
  if (i < NN) row_ptr[i] = buf[threadIdx.x] - v;  // block-local exclusive
  if (threadIdx.x == SCAN_B - 1) bsum[blockIdx.x] = buf[SCAN_B - 1];
}

// scan the 98 block totals (inclusive -> exclusive, in place)
__global__ __launch_bounds__(128) void k_scan2(int* __restrict__ bsum) {
  __shared__ int buf[128];
  int v = (threadIdx.x < NBLK) ? bsum[threadIdx.x] : 0;
  buf[threadIdx.x] = v;
  __syncthreads();
  for (int off = 1; off < 128; off <<= 1) {
    int t = (threadIdx.x >= off) ? buf[threadIdx.x - off] : 0;
    __syncthreads();
    buf[threadIdx.x] += t;
    __syncthreads();
  }
  if (threadIdx.x < NBLK) bsum[threadIdx.x] = buf[threadIdx.x] - v;
}

// add block offsets, init cur, close row_ptr
__global__ __launch_bounds__(SCAN_B) void k_scan3(int* __restrict__ row_ptr,
                                                  int* __restrict__ cur,
                                                  const int* __restrict__ bsum) {
  int i = blockIdx.x * SCAN_B + threadIdx.x;
  if (i < NN) {
    int rp = row_ptr[i] + bsum[blockIdx.x];
    row_ptr[i] = rp;
    cur[i] = rp;
  }
  if (i == 0) row_ptr[NN] = NE;  // every edge has dst in [0,NN)
}

__global__ __launch_bounds__(256) void k_scatter(const int* __restrict__ src,
                                                 const int* __restrict__ dst,
                                                 int* __restrict__ cur,
                                                 int* __restrict__ col) {
  int i = blockIdx.x * 256 + threadIdx.x;
  if (i < NE) {
    int d = dst[i];
    int p = atomicAdd(&cur[d], 1);
    col[p] = src[i];
  }
}

// ---------------- Encoder: h = x @ W_enc + b_enc ----------------
__global__ __launch_bounds__(256) void k_encoder(const float* __restrict__ x,
                                                 const float* __restrict__ W,
                                                 const float* __restrict__ b,
                                                 float* __restrict__ h) {
  int lane = threadIdx.x & 63;
  float wc[DIN];
#pragma unroll
  for (int k = 0; k < DIN; ++k) wc[k] = W[k * DH + lane];
  float bj = b[lane];
  int wid = (blockIdx.x * blockDim.x + threadIdx.x) >> 6;
  int nw = (gridDim.x * blockDim.x) >> 6;
  for (int n = wid; n < NN; n += nw) {
    float v0 = x[n * DIN + lane];
    float v1 = x[n * DIN + 64 + lane];
    float acc = bj;
#pragma unroll
    for (int k = 0; k < 64; ++k) acc = fmaf(lane_bcast(v0, k), wc[k], acc);
#pragma unroll
    for (int k = 0; k < 64; ++k) acc = fmaf(lane_bcast(v1, k), wc[64 + k], acc);
    h[n * DH + lane] = acc;
  }
}

// ---------------- Fused layer: [BN+ReLU] -> GENConv(softmax agg) -> GEMM
//                  (+res) -> col-stats of output ----------------
// stats_in == null  => layer 0: no BN, combine uses raw h (no relu)
// messages: relu(bn_relu(h))+eps == bn_relu(h)+eps (idempotent relu)
// softmax without max-subtraction: msg in [eps, ~O(10)] so exp() is safe in f32
__global__ __launch_bounds__(256) void k_layer(
    const float* __restrict__ h_pre, const float* __restrict__ stats_in,
    const float* __restrict__ gamma, const float* __restrict__ beta,
    const int* __restrict__ row_ptr, const int* __restrict__ col,
    const float* __restrict__ W, const float* __restrict__ b, int add_res,
    float* __restrict__ hout, float* __restrict__ stats_out) {
  int lane = threadIdx.x & 63;
  float scale = 1.f, shift = 0.f;
  if (stats_in) {
    float mu = stats_in[lane] * (1.0f / NN);
    float var = stats_in[64 + lane] * (1.0f / NN) - mu * mu;
    scale = gamma[lane] * rsqrtf(var + 1e-5f);
    shift = beta[lane] - mu * scale;
  }
  float wc[DH];
#pragma unroll
  for (int k = 0; k < DH; ++k) wc[k] = W[k * DH + lane];
  float bj = b[lane];
  const float* hl = h_pre + lane;
  float ssum = 0.f, sqsum = 0.f;
  int wid = (blockIdx.x * blockDim.x + threadIdx.x) >> 6;
  int nw = (gridDim.x * blockDim.x) >> 6;
  for (int n = wid; n < NN; n += nw) {
    int beg = row_ptr[n], end = row_ptr[n + 1];
    float s = 0.f, t = 0.f;
    int j = beg;
    for (; j + 4 <= end; j += 4) {  // 4 gathers in flight
      int c0 = col[j], c1 = col[j + 1], c2 = col[j + 2], c3 = col[j + 3];
      float r0 = hl[c0 * DH], r1 = hl[c1 * DH];
      float r2 = hl[c2 * DH], r3 = hl[c3 * DH];
      float v0 = fmaxf(fmaf(r0, scale, shift), 0.f) + 1e-7f;
      float v1 = fmaxf(fmaf(r1, scale, shift), 0.f) + 1e-7f;
      float v2 = fmaxf(fmaf(r2, scale, shift), 0.f) + 1e-7f;
      float v3 = fmaxf(fmaf(r3, scale, shift), 0.f) + 1e-7f;
      float e0 = __expf(v0), e1 = __expf(v1);
      float e2 = __expf(v2), e3 = __expf(v3);
      s += (e0 + e1) + (e2 + e3);
      t = fmaf(e0, v0, fmaf(e1, v1, fmaf(e2, v2, fmaf(e3, v3, t))));
    }
    for (; j < end; ++j) {
      int c = col[j];
      float v = fmaxf(fmaf(hl[c * DH], scale, shift), 0.f) + 1e-7f;
      float e = __expf(v);
      s += e;
      t = fmaf(e, v, t);
    }
    float aggv = t / (s + 1e-16f);
    float raw = hl[n * DH];
    float v = stats_in ? fmaxf(fmaf(raw, scale, shift), 0.f) : raw;
    v += aggv;
    float acc = bj;
#pragma unroll
    for (int k = 0; k < DH; ++k) acc = fmaf(lane_bcast(v, k), wc[k], acc);
    if (add_res) acc += raw;
    hout[n * DH + lane] = acc;
    ssum += acc;
    sqsum = fmaf(acc, acc, sqsum);
  }
  // column-stats epilogue for next layer's BN
  __shared__ float ls[256], lq[256];
  ls[threadIdx.x] = ssum;
  lq[threadIdx.x] = sqsum;
  __syncthreads();
  if (threadIdx.x < 64) {
    float s4 = ls[lane] + ls[lane + 64] + ls[lane + 128] + ls[lane + 192];
    float q4 = lq[lane] + lq[lane + 64] + lq[lane + 128] + lq[lane + 192];
    atomicAdd(&stats_out[lane], s4);
    atomicAdd(&stats_out[64 + lane], q4);
  }
}

// ---------------- Final BN+ReLU + prediction head + log_softmax ----------------
__global__ __launch_bounds__(256) void k_pred(
    const float* __restrict__ h_pre, const float* __restrict__ stats_in,
    const float* __restrict__ gamma, const float* __restrict__ beta,
    const float* __restrict__ Wp, const float* __restrict__ bp,
    float* __restrict__ out) {
  int lane = threadIdx.x & 63;
  float mu = stats_in[lane] * (1.0f / NN);
  float var = stats_in[64 + lane] * (1.0f / NN) - mu * mu;
  float scale = gamma[lane] * rsqrtf(var + 1e-5f);
  float shift = beta[lane] - mu * scale;
  int lc = lane < DOUT ? lane : DOUT - 1;
  float wc[DH];
#pragma unroll
  for (int k = 0; k < DH; ++k) wc[k] = Wp[k * DOUT + lc];
  float bj = bp[lc];
  int wid = (blockIdx.x * blockDim.x + threadIdx.x) >> 6;
  int nw = (gridDim.x * blockDim.x) >> 6;
  for (int n = wid; n < NN; n += nw) {
    float raw = h_pre[n * DH + lane];
    float v = fmaxf(fmaf(raw, scale, shift), 0.f);
    float acc = bj;
#pragma unroll
    for (int k = 0; k < DH; ++k) acc = fmaf(lane_bcast(v, k), wc[k], acc);
    float xm = (lane < DOUT) ? acc : -INFINITY;
#pragma unroll
    for (int o = 32; o >= 1; o >>= 1) xm = fmaxf(xm, __shfl_xor(xm, o, 64));
    float e = (lane < DOUT) ? __expf(acc - xm) : 0.f;
#pragma unroll
    for (int o = 32; o >= 1; o >>= 1) e += __shfl_xor(e, o, 64);
    if (lane < DOUT) out[n * DOUT + lane] = acc - xm - __logf(e);
  }
}

extern "C" void kernel_launch(void* const* d_in, const int* in_sizes, int n_in,
                              void* d_out, int out_size, void* d_ws, size_t ws_size,
                              hipStream_t stream) {
  const float* x      = (const float*)d_in[0];
  const int*   ei     = (const int*)d_in[1];
  const float* W_enc  = (const float*)d_in[2];
  const float* b_enc  = (const float*)d_in[3];
  const float* Wg     = (const float*)d_in[4];
  const float* bg     = (const float*)d_in[5];
  const float* gamma  = (const float*)d_in[6];
  const float* beta   = (const float*)d_in[7];
  const float* W_pred = (const float*)d_in[8];
  const float* b_pred = (const float*)d_in[9];
  float* out = (float*)d_out;

  const int* src = ei;
  const int* dst = ei + NE;

  char* p = (char*)d_ws;
  auto alloc = [&](size_t bytes) -> void* {
    void* r = (void*)p;
    p += (bytes + 255) & ~(size_t)255;
    return r;
  };
  float* hA      = (float*)alloc((size_t)NN * DH * 4);
  float* hB      = (float*)alloc((size_t)NN * DH * 4);
  int*   row_ptr = (int*)alloc((size_t)(NN + 1) * 4);
  int*   cur     = (int*)alloc((size_t)NN * 4);
  int*   cnt     = (int*)alloc((size_t)NN * 4);
  int*   col     = (int*)alloc((size_t)NE * 4);
  int*   bsum    = (int*)alloc((size_t)NBLK * 4);
  float* stats   = (float*)alloc((size_t)NL * 128 * 4);  // stats[l] = colsum/colsumsq of layer-l output

  hipMemsetAsync(cnt, 0, (size_t)NN * 4, stream);
  hipMemsetAsync(stats, 0, (size_t)NL * 128 * 4, stream);

  // ---- CSR build ----
  k_count<<<(NE + 255) / 256, 256, 0, stream>>>(dst, cnt);
  k_scan1<<<NBLK, SCAN_B, 0, stream>>>(cnt, row_ptr, bsum);
  k_scan2<<<1, 128, 0, stream>>>(bsum);
  k_scan3<<<NBLK, SCAN_B, 0, stream>>>(row_ptr, cur, bsum);
  k_scatter<<<(NE + 255) / 256, 256, 0, stream>>>(src, dst, cur, col);

  // ---- Encoder ----
  k_encoder<<<1024, 256, 0, stream>>>(x, W_enc, b_enc, hA);

  const int LAYER_BLOCKS = 2048;

  // ---- Layer 0 (no BN; combine uses raw h) ----
  k_layer<<<LAYER_BLOCKS, 256, 0, stream>>>(
      hA, nullptr, nullptr, nullptr, row_ptr, col, Wg, bg, 0, hB, stats);

  float* h = hB;
  float* hn = hA;
  for (int l = 1; l < NL; ++l) {
    k_layer<<<LAYER_BLOCKS, 256, 0, stream>>>(
        h, stats + (size_t)(l - 1) * 128,
        gamma + (size_t)(l - 1) * DH, beta + (size_t)(l - 1) * DH,
        row_ptr, col, Wg + (size_t)l * DH * DH, bg + (size_t)l * DH, 1,
        hn, stats + (size_t)l * 128);
    float* tmp = h; h = hn; hn = tmp;
  }

  // ---- Final BN + ReLU + prediction + log_softmax ----
  k_pred<<<1024, 256, 0, stream>>>(
      h, stats + (size_t)(NL - 1) * 128,
      gamma + (size_t)(NL - 1) * DH, beta + (size_t)(NL - 1) * DH,
      W_pred, b_pred, out);
}

// Round 5
// 1019.735 us; speedup vs baseline: 1.6403x; 1.0053x over previous
//
#include <hip/hip_runtime.h>
#include <math.h>

#define NN 100000
#define NE 1000000
#define DH 64
#define DIN 128
#define DOUT 40
#define NL 7
#define SCAN_B 1024
#define NBLK ((NN + SCAN_B - 1) / SCAN_B)  // 98

__device__ __forceinline__ float lane_bcast(float v, int l) {
  return __int_as_float(__builtin_amdgcn_readlane(__float_as_int(v), l));
}

// ---------------- CSR build ----------------
__global__ __launch_bounds__(256) void k_count(const int* __restrict__ dst,
                                               int* __restrict__ cnt) {
  int i = blockIdx.x * 256 + threadIdx.x;
  if (i < NE) atomicAdd(&cnt[dst[i]], 1);
}

__global__ __launch_bounds__(SCAN_B) void k_scan1(const int* __restrict__ cnt,
                                                  int* __restrict__ row_ptr,
                                                  int* __restrict__ bsum) {
  __shared__ int buf[SCAN_B];
  int i = blockIdx.x * SCAN_B + threadIdx.x;
  int v = (i < NN) ? cnt[i] : 0;
  buf[threadIdx.x] = v;
  __syncthreads();
  for (int off = 1; off < SCAN_B; off <<= 1) {
    int t = (threadIdx.x >= off) ? buf[threadIdx.x - off] : 0;
    __syncthreads();
    buf[threadIdx.x] += t;
    __syncthreads();
  }
  if (i < NN) row_ptr[i] = buf[threadIdx.x] - v;
  if (threadIdx.x == SCAN_B - 1) bsum[blockIdx.x] = buf[SCAN_B - 1];
}

__global__ __launch_bounds__(128) void k_scan2(int* __restrict__ bsum) {
  __shared__ int buf[128];
  int v = (threadIdx.x < NBLK) ? bsum[threadIdx.x] : 0;
  buf[threadIdx.x] = v;
  __syncthreads();
  for (int off = 1; off < 128; off <<= 1) {
    int t = (threadIdx.x >= off) ? buf[threadIdx.x - off] : 0;
    __syncthreads();
    buf[threadIdx.x] += t;
    __syncthreads();
  }
  if (threadIdx.x < NBLK) bsum[threadIdx.x] = buf[threadIdx.x] - v;
}

__global__ __launch_bounds__(SCAN_B) void k_scan3(int* __restrict__ row_ptr,
                                                  int* __restrict__ cur,
                                                  const int* __restrict__ bsum) {
  int i = blockIdx.x * SCAN_B + threadIdx.x;
  if (i < NN) {
    int rp = row_ptr[i] + bsum[blockIdx.x];
    row_ptr[i] = rp;
    cur[i] = rp;
  }
  if (i == 0) row_ptr[NN] = NE;
}

__global__ __launch_bounds__(256) void k_scatter(const int* __restrict__ src,
                                                 const int* __restrict__ dst,
                                                 int* __restrict__ cur,
                                                 int* __restrict__ col) {
  int i = blockIdx.x * 256 + threadIdx.x;
  if (i < NE) {
    int d = dst[i];
    int p = atomicAdd(&cur[d], 1);
    col[p] = src[i];
  }
}

// ---------------- Encoder: h = x @ W_enc + b_enc ----------------
__global__ __launch_bounds__(256) void k_encoder(const float* __restrict__ x,
                                                 const float* __restrict__ W,
                                                 const float* __restrict__ b,
                                                 float* __restrict__ h) {
  int lane = threadIdx.x & 63;
  float wc[DIN];
#pragma unroll
  for (int k = 0; k < DIN; ++k) wc[k] = W[k * DH + lane];
  float bj = b[lane];
  int wid = (blockIdx.x * blockDim.x + threadIdx.x) >> 6;
  int nw = (gridDim.x * blockDim.x) >> 6;
  for (int n = wid; n < NN; n += nw) {
    float v0 = x[n * DIN + lane];
    float v1 = x[n * DIN + 64 + lane];
    float acc = bj;
#pragma unroll
    for (int k = 0; k < 64; ++k) acc = fmaf(lane_bcast(v0, k), wc[k], acc);
#pragma unroll
    for (int k = 0; k < 64; ++k) acc = fmaf(lane_bcast(v1, k), wc[64 + k], acc);
    h[n * DH + lane] = acc;
  }
}

// ---------------- Message precompute: msg = f16(relu(bn(h)) + eps) ----------------
// stats_in == null => layer 0: msg = f16(relu(h) + eps)
__global__ __launch_bounds__(256) void k_msg(const float* __restrict__ h,
                                             const float* __restrict__ stats_in,
                                             const float* __restrict__ gamma,
                                             const float* __restrict__ beta,
                                             _Float16* __restrict__ msg) {
  int lane = threadIdx.x & 63;
  float scale = 1.f, shift = 0.f;
  if (stats_in) {
    float mu = stats_in[lane] * (1.0f / NN);
    float var = stats_in[64 + lane] * (1.0f / NN) - mu * mu;
    scale = gamma[lane] * rsqrtf(var + 1e-5f);
    shift = beta[lane] - mu * scale;
  }
  int wid = (blockIdx.x * blockDim.x + threadIdx.x) >> 6;
  int nw = (gridDim.x * blockDim.x) >> 6;
  for (int n = wid; n < NN; n += nw) {
    float r = h[n * DH + lane];
    float v = fmaxf(fmaf(r, scale, shift), 0.f) + 1e-7f;
    msg[n * DH + lane] = (_Float16)v;
  }
}

// ---------------- Fused layer: gather(softmax agg over f16 msg) -> combine
//                  -> GEMM (+res) -> col-stats of output ----------------
__global__ __launch_bounds__(256) void k_layer(
    const float* __restrict__ h_pre, const _Float16* __restrict__ msg,
    const float* __restrict__ stats_in,
    const float* __restrict__ gamma, const float* __restrict__ beta,
    const int* __restrict__ row_ptr, const int* __restrict__ col,
    const float* __restrict__ W, const float* __restrict__ b, int add_res,
    float* __restrict__ hout, float* __restrict__ stats_out) {
  int lane = threadIdx.x & 63;
  float scale = 1.f, shift = 0.f;
  if (stats_in) {
    float mu = stats_in[lane] * (1.0f / NN);
    float var = stats_in[64 + lane] * (1.0f / NN) - mu * mu;
    scale = gamma[lane] * rsqrtf(var + 1e-5f);
    shift = beta[lane] - mu * scale;
  }
  float wc[DH];
#pragma unroll
  for (int k = 0; k < DH; ++k) wc[k] = W[k * DH + lane];
  float bj = b[lane];
  const float* hl = h_pre + lane;
  const _Float16* ml = msg + lane;
  float ssum = 0.f, sqsum = 0.f;
  int wid = (blockIdx.x * blockDim.x + threadIdx.x) >> 6;
  int nw = (gridDim.x * blockDim.x) >> 6;
  for (int n = wid; n < NN; n += nw) {
    int beg = row_ptr[n], end = row_ptr[n + 1];
    float s = 0.f, t = 0.f;
    int j = beg;
    for (; j + 8 <= end; j += 8) {  // 8 gathers in flight
      int c0 = col[j], c1 = col[j + 1], c2 = col[j + 2], c3 = col[j + 3];
      int c4 = col[j + 4], c5 = col[j + 5], c6 = col[j + 6], c7 = col[j + 7];
      float v0 = (float)ml[c0 * DH], v1 = (float)ml[c1 * DH];
      float v2 = (float)ml[c2 * DH], v3 = (float)ml[c3 * DH];
      float v4 = (float)ml[c4 * DH], v5 = (float)ml[c5 * DH];
      float v6 = (float)ml[c6 * DH], v7 = (float)ml[c7 * DH];
      float e0 = __expf(v0), e1 = __expf(v1), e2 = __expf(v2), e3 = __expf(v3);
      float e4 = __expf(v4), e5 = __expf(v5), e6 = __expf(v6), e7 = __expf(v7);
      s += ((e0 + e1) + (e2 + e3)) + ((e4 + e5) + (e6 + e7));
      t = fmaf(e0, v0, fmaf(e1, v1, fmaf(e2, v2, fmaf(e3, v3, t))));
      t = fmaf(e4, v4, fmaf(e5, v5, fmaf(e6, v6, fmaf(e7, v7, t))));
    }
    for (; j + 4 <= end; j += 4) {
      int c0 = col[j], c1 = col[j + 1], c2 = col[j + 2], c3 = col[j + 3];
      float v0 = (float)ml[c0 * DH], v1 = (float)ml[c1 * DH];
      float v2 = (float)ml[c2 * DH], v3 = (float)ml[c3 * DH];
      float e0 = __expf(v0), e1 = __expf(v1), e2 = __expf(v2), e3 = __expf(v3);
      s += (e0 + e1) + (e2 + e3);
      t = fmaf(e0, v0, fmaf(e1, v1, fmaf(e2, v2, fmaf(e3, v3, t))));
    }
    for (; j < end; ++j) {
      float v = (float)ml[col[j] * DH];
      float e = __expf(v);
      s += e;
      t = fmaf(e, v, t);
    }
    float aggv = t / (s + 1e-16f);
    float raw = hl[n * DH];
    float v = stats_in ? fmaxf(fmaf(raw, scale, shift), 0.f) : raw;
    v += aggv;
    float acc = bj;
#pragma unroll
    for (int k = 0; k < DH; ++k) acc = fmaf(lane_bcast(v, k), wc[k], acc);
    if (add_res) acc += raw;
    hout[n * DH + lane] = acc;
    ssum += acc;
    sqsum = fmaf(acc, acc, sqsum);
  }
  // column-stats epilogue for next layer's BN
  __shared__ float ls[256], lq[256];
  ls[threadIdx.x] = ssum;
  lq[threadIdx.x] = sqsum;
  __syncthreads();
  if (threadIdx.x < 64) {
    float s4 = ls[lane] + ls[lane + 64] + ls[lane + 128] + ls[lane + 192];
    float q4 = lq[lane] + lq[lane + 64] + lq[lane + 128] + lq[lane + 192];
    atomicAdd(&stats_out[lane], s4);
    atomicAdd(&stats_out[64 + lane], q4);
  }
}

// ---------------- Final BN+ReLU + prediction head + log_softmax ----------------
__global__ __launch_bounds__(256) void k_pred(
    const float* __restrict__ h_pre, const float* __restrict__ stats_in,
    const float* __restrict__ gamma, const float* __restrict__ beta,
    const float* __restrict__ Wp, const float* __restrict__ bp,
    float* __restrict__ out) {
  int lane = threadIdx.x & 63;
  float mu = stats_in[lane] * (1.0f / NN);
  float var = stats_in[64 + lane] * (1.0f / NN) - mu * mu;
  float scale = gamma[lane] * rsqrtf(var + 1e-5f);
  float shift = beta[lane] - mu * scale;
  int lc = lane < DOUT ? lane : DOUT - 1;
  float wc[DH];
#pragma unroll
  for (int k = 0; k < DH; ++k) wc[k] = Wp[k * DOUT + lc];
  float bj = bp[lc];
  int wid = (blockIdx.x * blockDim.x + threadIdx.x) >> 6;
  int nw = (gridDim.x * blockDim.x) >> 6;
  for (int n = wid; n < NN; n += nw) {
    float raw = h_pre[n * DH + lane];
    float v = fmaxf(fmaf(raw, scale, shift), 0.f);
    float acc = bj;
#pragma unroll
    for (int k = 0; k < DH; ++k) acc = fmaf(lane_bcast(v, k), wc[k], acc);
    float xm = (lane < DOUT) ? acc : -INFINITY;
#pragma unroll
    for (int o = 32; o >= 1; o >>= 1) xm = fmaxf(xm, __shfl_xor(xm, o, 64));
    float e = (lane < DOUT) ? __expf(acc - xm) : 0.f;
#pragma unroll
    for (int o = 32; o >= 1; o >>= 1) e += __shfl_xor(e, o, 64);
    if (lane < DOUT) out[n * DOUT + lane] = acc - xm - __logf(e);
  }
}

extern "C" void kernel_launch(void* const* d_in, const int* in_sizes, int n_in,
                              void* d_out, int out_size, void* d_ws, size_t ws_size,
                              hipStream_t stream) {
  const float* x      = (const float*)d_in[0];
  const int*   ei     = (const int*)d_in[1];
  const float* W_enc  = (const float*)d_in[2];
  const float* b_enc  = (const float*)d_in[3];
  const float* Wg     = (const float*)d_in[4];
  const float* bg     = (const float*)d_in[5];
  const float* gamma  = (const float*)d_in[6];
  const float* beta   = (const float*)d_in[7];
  const float* W_pred = (const float*)d_in[8];
  const float* b_pred = (const float*)d_in[9];
  float* out = (float*)d_out;

  const int* src = ei;
  const int* dst = ei + NE;

  char* p = (char*)d_ws;
  auto alloc = [&](size_t bytes) -> void* {
    void* r = (void*)p;
    p += (bytes + 255) & ~(size_t)255;
    return r;
  };
  float*     hA      = (float*)alloc((size_t)NN * DH * 4);
  float*     hB      = (float*)alloc((size_t)NN * DH * 4);
  _Float16*  msg     = (_Float16*)alloc((size_t)NN * DH * 2);
  int*       row_ptr = (int*)alloc((size_t)(NN + 1) * 4);
  int*       cur     = (int*)alloc((size_t)NN * 4);
  int*       cnt     = (int*)alloc((size_t)NN * 4);
  int*       col     = (int*)alloc((size_t)NE * 4);
  int*       bsum    = (int*)alloc((size_t)NBLK * 4);
  float*     stats   = (float*)alloc((size_t)NL * 128 * 4);

  hipMemsetAsync(cnt, 0, (size_t)NN * 4, stream);
  hipMemsetAsync(stats, 0, (size_t)NL * 128 * 4, stream);

  // ---- CSR build ----
  k_count<<<(NE + 255) / 256, 256, 0, stream>>>(dst, cnt);
  k_scan1<<<NBLK, SCAN_B, 0, stream>>>(cnt, row_ptr, bsum);
  k_scan2<<<1, 128, 0, stream>>>(bsum);
  k_scan3<<<NBLK, SCAN_B, 0, stream>>>(row_ptr, cur, bsum);
  k_scatter<<<(NE + 255) / 256, 256, 0, stream>>>(src, dst, cur, col);

  // ---- Encoder ----
  k_encoder<<<1024, 256, 0, stream>>>(x, W_enc, b_enc, hA);

  const int LAYER_BLOCKS = 2048;
  const int MSG_BLOCKS = 1024;

  // ---- Layer 0 (no BN; combine uses raw h; msg = relu(h)+eps) ----
  k_msg<<<MSG_BLOCKS, 256, 0, stream>>>(hA, nullptr, nullptr, nullptr, msg);
  k_layer<<<LAYER_BLOCKS, 256, 0, stream>>>(
      hA, msg, nullptr, nullptr, nullptr, row_ptr, col, Wg, bg, 0, hB, stats);

  float* h = hB;
  float* hn = hA;
  for (int l = 1; l < NL; ++l) {
    const float* st = stats + (size_t)(l - 1) * 128;
    const float* g  = gamma + (size_t)(l - 1) * DH;
    const float* be = beta + (size_t)(l - 1) * DH;
    k_msg<<<MSG_BLOCKS, 256, 0, stream>>>(h, st, g, be, msg);
    k_layer<<<LAYER_BLOCKS, 256, 0, stream>>>(
        h, msg, st, g, be, row_ptr, col,
        Wg + (size_t)l * DH * DH, bg + (size_t)l * DH, 1,
        hn, stats + (size_t)l * 128);
    float* tmp = h; h = hn; hn = tmp;
  }

  // ---- Final BN + ReLU + prediction + log_softmax ----
  k_pred<<<1024, 256, 0, stream>>>(
      h, stats + (size_t)(NL - 1) * 128,
      gamma + (size_t)(NL - 1) * DH, beta + (size_t)(NL - 1) * DH,
      W_pred, b_pred, out);
}

// Round 6
// 928.016 us; speedup vs baseline: 1.8024x; 1.0988x over previous
//
#include <hip/hip_runtime.h>
#include <math.h>

#define NN 100000
#define NE 1000000
#define DH 64
#define DIN 128
#define DOUT 40
#define NL 7
#define SCAN_B 1024
#define NBLK ((NN + SCAN_B - 1) / SCAN_B)  // 98
#define GW 16  // gather width per round (masked; covers deg<=16 in one round)

__device__ __forceinline__ float lane_bcast(float v, int l) {
  return __int_as_float(__builtin_amdgcn_readlane(__float_as_int(v), l));
}

// ---------------- CSR build ----------------
__global__ __launch_bounds__(256) void k_count(const int* __restrict__ dst,
                                               int* __restrict__ cnt) {
  int i = blockIdx.x * 256 + threadIdx.x;
  if (i < NE) atomicAdd(&cnt[dst[i]], 1);
}

__global__ __launch_bounds__(SCAN_B) void k_scan1(const int* __restrict__ cnt,
                                                  int* __restrict__ row_ptr,
                                                  int* __restrict__ bsum) {
  __shared__ int buf[SCAN_B];
  int i = blockIdx.x * SCAN_B + threadIdx.x;
  int v = (i < NN) ? cnt[i] : 0;
  buf[threadIdx.x] = v;
  __syncthreads();
  for (int off = 1; off < SCAN_B; off <<= 1) {
    int t = (threadIdx.x >= off) ? buf[threadIdx.x - off] : 0;
    __syncthreads();
    buf[threadIdx.x] += t;
    __syncthreads();
  }
  if (i < NN) row_ptr[i] = buf[threadIdx.x] - v;
  if (threadIdx.x == SCAN_B - 1) bsum[blockIdx.x] = buf[SCAN_B - 1];
}

__global__ __launch_bounds__(128) void k_scan2(int* __restrict__ bsum) {
  __shared__ int buf[128];
  int v = (threadIdx.x < NBLK) ? bsum[threadIdx.x] : 0;
  buf[threadIdx.x] = v;
  __syncthreads();
  for (int off = 1; off < 128; off <<= 1) {
    int t = (threadIdx.x >= off) ? buf[threadIdx.x - off] : 0;
    __syncthreads();
    buf[threadIdx.x] += t;
    __syncthreads();
  }
  if (threadIdx.x < NBLK) bsum[threadIdx.x] = buf[threadIdx.x] - v;
}

__global__ __launch_bounds__(SCAN_B) void k_scan3(int* __restrict__ row_ptr,
                                                  int* __restrict__ cur,
                                                  const int* __restrict__ bsum) {
  int i = blockIdx.x * SCAN_B + threadIdx.x;
  if (i < NN) {
    int rp = row_ptr[i] + bsum[blockIdx.x];
    row_ptr[i] = rp;
    cur[i] = rp;
  }
  if (i == 0) row_ptr[NN] = NE;
}

__global__ __launch_bounds__(256) void k_scatter(const int* __restrict__ src,
                                                 const int* __restrict__ dst,
                                                 int* __restrict__ cur,
                                                 int* __restrict__ col) {
  int i = blockIdx.x * 256 + threadIdx.x;
  if (i < NE) {
    int d = dst[i];
    int p = atomicAdd(&cur[d], 1);
    col[p] = src[i];
  }
}

// ---------------- Encoder: h = x @ W_enc + b_enc ----------------
__global__ __launch_bounds__(256) void k_encoder(const float* __restrict__ x,
                                                 const float* __restrict__ W,
                                                 const float* __restrict__ b,
                                                 float* __restrict__ h) {
  int lane = threadIdx.x & 63;
  float wc[DIN];
#pragma unroll
  for (int k = 0; k < DIN; ++k) wc[k] = W[k * DH + lane];
  float bj = b[lane];
  int wid = (blockIdx.x * blockDim.x + threadIdx.x) >> 6;
  int nw = (gridDim.x * blockDim.x) >> 6;
  for (int n = wid; n < NN; n += nw) {
    float v0 = x[n * DIN + lane];
    float v1 = x[n * DIN + 64 + lane];
    float acc = bj;
#pragma unroll
    for (int k = 0; k < 64; ++k) acc = fmaf(lane_bcast(v0, k), wc[k], acc);
#pragma unroll
    for (int k = 0; k < 64; ++k) acc = fmaf(lane_bcast(v1, k), wc[64 + k], acc);
    h[n * DH + lane] = acc;
  }
}

// ---------------- Message precompute: msg = f16(relu(bn(h)) + eps) ----------------
__global__ __launch_bounds__(256) void k_msg(const float* __restrict__ h,
                                             const float* __restrict__ stats_in,
                                             const float* __restrict__ gamma,
                                             const float* __restrict__ beta,
                                             _Float16* __restrict__ msg) {
  int lane = threadIdx.x & 63;
  float scale = 1.f, shift = 0.f;
  if (stats_in) {
    float mu = stats_in[lane] * (1.0f / NN);
    float var = stats_in[64 + lane] * (1.0f / NN) - mu * mu;
    scale = gamma[lane] * rsqrtf(var + 1e-5f);
    shift = beta[lane] - mu * scale;
  }
  int wid = (blockIdx.x * blockDim.x + threadIdx.x) >> 6;
  int nw = (gridDim.x * blockDim.x) >> 6;
  for (int n = wid; n < NN; n += nw) {
    float r = h[n * DH + lane];
    float v = fmaxf(fmaf(r, scale, shift), 0.f) + 1e-7f;
    msg[n * DH + lane] = (_Float16)v;
  }
}

// ---------------- Fused layer: gather(softmax agg, 16-wide masked) -> combine
//                  -> GEMM (weights in LDS) (+res) -> col-stats of output ----------------
__global__ __launch_bounds__(256) void k_layer(
    const float* __restrict__ h_pre, const _Float16* __restrict__ msg,
    const float* __restrict__ stats_in,
    const float* __restrict__ gamma, const float* __restrict__ beta,
    const int* __restrict__ row_ptr, const int* __restrict__ col,
    const float* __restrict__ W, const float* __restrict__ b, int add_res,
    float* __restrict__ hout, float* __restrict__ stats_out) {
  __shared__ float Wlds[DH * DH];  // 16 KB; reused for stats reduce at the end
  for (int i = threadIdx.x; i < DH * DH; i += 256) Wlds[i] = W[i];
  __syncthreads();

  int lane = threadIdx.x & 63;
  float scale = 1.f, shift = 0.f;
  if (stats_in) {
    float mu = stats_in[lane] * (1.0f / NN);
    float var = stats_in[64 + lane] * (1.0f / NN) - mu * mu;
    scale = gamma[lane] * rsqrtf(var + 1e-5f);
    shift = beta[lane] - mu * scale;
  }
  float bj = b[lane];
  const float* hl = h_pre + lane;
  const _Float16* ml = msg + lane;
  float ssum = 0.f, sqsum = 0.f;
  int wid = (blockIdx.x * blockDim.x + threadIdx.x) >> 6;
  int nw = (gridDim.x * blockDim.x) >> 6;
  for (int n = wid; n < NN; n += nw) {
    int beg = row_ptr[n], end = row_ptr[n + 1];
    float raw = hl[n * DH];  // issue early; independent of gathers
    float s = 0.f, t = 0.f;
    for (int j = beg; j < end; j += GW) {
      int rem = end - j;  // wave-uniform
      int cc[GW];
#pragma unroll
      for (int k = 0; k < GW; ++k) cc[k] = col[(k < rem) ? j + k : end - 1];
      float vv[GW];
#pragma unroll
      for (int k = 0; k < GW; ++k) vv[k] = (float)ml[cc[k] * DH];
#pragma unroll
      for (int k = 0; k < GW; ++k) {
        float e = (k < rem) ? __expf(vv[k]) : 0.f;
        s += e;
        t = fmaf(e, vv[k], t);
      }
    }
    float aggv = t / (s + 1e-16f);
    float v = stats_in ? fmaxf(fmaf(raw, scale, shift), 0.f) : raw;
    v += aggv;
    float acc = bj;
#pragma unroll
    for (int k = 0; k < DH; ++k)
      acc = fmaf(lane_bcast(v, k), Wlds[k * DH + lane], acc);
    if (add_res) acc += raw;
    hout[n * DH + lane] = acc;
    ssum += acc;
    sqsum = fmaf(acc, acc, sqsum);
  }
  // column-stats epilogue for next layer's BN (reuse Wlds as scratch)
  __syncthreads();
  Wlds[threadIdx.x] = ssum;
  Wlds[256 + threadIdx.x] = sqsum;
  __syncthreads();
  if (threadIdx.x < 64) {
    float s4 = Wlds[lane] + Wlds[lane + 64] + Wlds[lane + 128] + Wlds[lane + 192];
    float q4 = Wlds[256 + lane] + Wlds[256 + lane + 64] + Wlds[256 + lane + 128] +
               Wlds[256 + lane + 192];
    atomicAdd(&stats_out[lane], s4);
    atomicAdd(&stats_out[64 + lane], q4);
  }
}

// ---------------- Final BN+ReLU + prediction head + log_softmax ----------------
__global__ __launch_bounds__(256) void k_pred(
    const float* __restrict__ h_pre, const float* __restrict__ stats_in,
    const float* __restrict__ gamma, const float* __restrict__ beta,
    const float* __restrict__ Wp, const float* __restrict__ bp,
    float* __restrict__ out) {
  int lane = threadIdx.x & 63;
  float mu = stats_in[lane] * (1.0f / NN);
  float var = stats_in[64 + lane] * (1.0f / NN) - mu * mu;
  float scale = gamma[lane] * rsqrtf(var + 1e-5f);
  float shift = beta[lane] - mu * scale;
  int lc = lane < DOUT ? lane : DOUT - 1;
  float wc[DH];
#pragma unroll
  for (int k = 0; k < DH; ++k) wc[k] = Wp[k * DOUT + lc];
  float bj = bp[lc];
  int wid = (blockIdx.x * blockDim.x + threadIdx.x) >> 6;
  int nw = (gridDim.x * blockDim.x) >> 6;
  for (int n = wid; n < NN; n += nw) {
    float raw = h_pre[n * DH + lane];
    float v = fmaxf(fmaf(raw, scale, shift), 0.f);
    float acc = bj;
#pragma unroll
    for (int k = 0; k < DH; ++k) acc = fmaf(lane_bcast(v, k), wc[k], acc);
    float xm = (lane < DOUT) ? acc : -INFINITY;
#pragma unroll
    for (int o = 32; o >= 1; o >>= 1) xm = fmaxf(xm, __shfl_xor(xm, o, 64));
    float e = (lane < DOUT) ? __expf(acc - xm) : 0.f;
#pragma unroll
    for (int o = 32; o >= 1; o >>= 1) e += __shfl_xor(e, o, 64);
    if (lane < DOUT) out[n * DOUT + lane] = acc - xm - __logf(e);
  }
}

extern "C" void kernel_launch(void* const* d_in, const int* in_sizes, int n_in,
                              void* d_out, int out_size, void* d_ws, size_t ws_size,
                              hipStream_t stream) {
  const float* x      = (const float*)d_in[0];
  const int*   ei     = (const int*)d_in[1];
  const float* W_enc  = (const float*)d_in[2];
  const float* b_enc  = (const float*)d_in[3];
  const float* Wg     = (const float*)d_in[4];
  const float* bg     = (const float*)d_in[5];
  const float* gamma  = (const float*)d_in[6];
  const float* beta   = (const float*)d_in[7];
  const float* W_pred = (const float*)d_in[8];
  const float* b_pred = (const float*)d_in[9];
  float* out = (float*)d_out;

  const int* src = ei;
  const int* dst = ei + NE;

  char* p = (char*)d_ws;
  auto alloc = [&](size_t bytes) -> void* {
    void* r = (void*)p;
    p += (bytes + 255) & ~(size_t)255;
    return r;
  };
  float*     hA      = (float*)alloc((size_t)NN * DH * 4);
  float*     hB      = (float*)alloc((size_t)NN * DH * 4);
  _Float16*  msg     = (_Float16*)alloc((size_t)NN * DH * 2);
  int*       row_ptr = (int*)alloc((size_t)(NN + 1) * 4);
  int*       cur     = (int*)alloc((size_t)NN * 4);
  int*       cnt     = (int*)alloc((size_t)NN * 4);
  int*       col     = (int*)alloc((size_t)NE * 4);
  int*       bsum    = (int*)alloc((size_t)NBLK * 4);
  float*     stats   = (float*)alloc((size_t)NL * 128 * 4);

  hipMemsetAsync(cnt, 0, (size_t)NN * 4, stream);
  hipMemsetAsync(stats, 0, (size_t)NL * 128 * 4, stream);

  // ---- CSR build ----
  k_count<<<(NE + 255) / 256, 256, 0, stream>>>(dst, cnt);
  k_scan1<<<NBLK, SCAN_B, 0, stream>>>(cnt, row_ptr, bsum);
  k_scan2<<<1, 128, 0, stream>>>(bsum);
  k_scan3<<<NBLK, SCAN_B, 0, stream>>>(row_ptr, cur, bsum);
  k_scatter<<<(NE + 255) / 256, 256, 0, stream>>>(src, dst, cur, col);

  // ---- Encoder ----
  k_encoder<<<1024, 256, 0, stream>>>(x, W_enc, b_enc, hA);

  const int LAYER_BLOCKS = 2048;
  const int MSG_BLOCKS = 1024;

  // ---- Layer 0 (no BN; combine uses raw h; msg = relu(h)+eps) ----
  k_msg<<<MSG_BLOCKS, 256, 0, stream>>>(hA, nullptr, nullptr, nullptr, msg);
  k_layer<<<LAYER_BLOCKS, 256, 0, stream>>>(
      hA, msg, nullptr, nullptr, nullptr, row_ptr, col, Wg, bg, 0, hB, stats);

  float* h = hB;
  float* hn = hA;
  for (int l = 1; l < NL; ++l) {
    const float* st = stats + (size_t)(l - 1) * 128;
    const float* g  = gamma + (size_t)(l - 1) * DH;
    const float* be = beta + (size_t)(l - 1) * DH;
    k_msg<<<MSG_BLOCKS, 256, 0, stream>>>(h, st, g, be, msg);
    k_layer<<<LAYER_BLOCKS, 256, 0, stream>>>(
        h, msg, st, g, be, row_ptr, col,
        Wg + (size_t)l * DH * DH, bg + (size_t)l * DH, 1,
        hn, stats + (size_t)l * 128);
    float* tmp = h; h = hn; hn = tmp;
  }

  // ---- Final BN + ReLU + prediction + log_softmax ----
  k_pred<<<1024, 256, 0, stream>>>(
      h, stats + (size_t)(NL - 1) * 128,
      gamma + (size_t)(NL - 1) * DH, beta + (size_t)(NL - 1) * DH,
      W_pred, b_pred, out);
}

// Round 7
// 912.869 us; speedup vs baseline: 1.8324x; 1.0166x over previous
//
#include <hip/hip_runtime.h>
#include <math.h>

#define NN 100000
#define NE 1000000
#define DH 64
#define DIN 128
#define DOUT 40
#define NL 7
#define SCAN_B 1024
#define NBLK ((NN + SCAN_B - 1) / SCAN_B)  // 98
#define GW 16              // gather width (masked); col[] is zero-padded by GW
#define NGRP (NN / 16)     // 6250 16-node groups (exact)
#define LBLK ((NGRP + 3) / 4)

typedef _Float16 v8h __attribute__((ext_vector_type(8)));
typedef float v4f __attribute__((ext_vector_type(4)));

__device__ __forceinline__ float lane_bcast(float v, int l) {
  return __int_as_float(__builtin_amdgcn_readlane(__float_as_int(v), l));
}

// ---------------- CSR build ----------------
__global__ __launch_bounds__(256) void k_count(const int* __restrict__ dst,
                                               int* __restrict__ cnt) {
  int i = blockIdx.x * 256 + threadIdx.x;
  if (i < NE) atomicAdd(&cnt[dst[i]], 1);
}

__global__ __launch_bounds__(SCAN_B) void k_scan1(const int* __restrict__ cnt,
                                                  int* __restrict__ row_ptr,
                                                  int* __restrict__ bsum) {
  __shared__ int buf[SCAN_B];
  int i = blockIdx.x * SCAN_B + threadIdx.x;
  int v = (i < NN) ? cnt[i] : 0;
  buf[threadIdx.x] = v;
  __syncthreads();
  for (int off = 1; off < SCAN_B; off <<= 1) {
    int t = (threadIdx.x >= off) ? buf[threadIdx.x - off] : 0;
    __syncthreads();
    buf[threadIdx.x] += t;
    __syncthreads();
  }
  if (i < NN) row_ptr[i] = buf[threadIdx.x] - v;
  if (threadIdx.x == SCAN_B - 1) bsum[blockIdx.x] = buf[SCAN_B - 1];
}

__global__ __launch_bounds__(128) void k_scan2(int* __restrict__ bsum) {
  __shared__ int buf[128];
  int v = (threadIdx.x < NBLK) ? bsum[threadIdx.x] : 0;
  buf[threadIdx.x] = v;
  __syncthreads();
  for (int off = 1; off < 128; off <<= 1) {
    int t = (threadIdx.x >= off) ? buf[threadIdx.x - off] : 0;
    __syncthreads();
    buf[threadIdx.x] += t;
    __syncthreads();
  }
  if (threadIdx.x < NBLK) bsum[threadIdx.x] = buf[threadIdx.x] - v;
}

__global__ __launch_bounds__(SCAN_B) void k_scan3(int* __restrict__ row_ptr,
                                                  int* __restrict__ cur,
                                                  const int* __restrict__ bsum) {
  int i = blockIdx.x * SCAN_B + threadIdx.x;
  if (i < NN) {
    int rp = row_ptr[i] + bsum[blockIdx.x];
    row_ptr[i] = rp;
    cur[i] = rp;
  }
  if (i == 0) row_ptr[NN] = NE;
}

// col stores BYTE offsets into the f16 msg array: src * DH * 2
__global__ __launch_bounds__(256) void k_scatter(const int* __restrict__ src,
                                                 const int* __restrict__ dst,
                                                 int* __restrict__ cur,
                                                 int* __restrict__ colb) {
  int i = blockIdx.x * 256 + threadIdx.x;
  if (i < NE) {
    int d = dst[i];
    int p = atomicAdd(&cur[d], 1);
    colb[p] = src[i] * (DH * 2);
  }
}

// ---------------- Encoder: h = x @ W_enc + b_enc ----------------
__global__ __launch_bounds__(256) void k_encoder(const float* __restrict__ x,
                                                 const float* __restrict__ W,
                                                 const float* __restrict__ b,
                                                 float* __restrict__ h) {
  int lane = threadIdx.x & 63;
  float wc[DIN];
#pragma unroll
  for (int k = 0; k < DIN; ++k) wc[k] = W[k * DH + lane];
  float bj = b[lane];
  int wid = (blockIdx.x * blockDim.x + threadIdx.x) >> 6;
  int nw = (gridDim.x * blockDim.x) >> 6;
  for (int n = wid; n < NN; n += nw) {
    float v0 = x[n * DIN + lane];
    float v1 = x[n * DIN + 64 + lane];
    float acc = bj;
#pragma unroll
    for (int k = 0; k < 64; ++k) acc = fmaf(lane_bcast(v0, k), wc[k], acc);
#pragma unroll
    for (int k = 0; k < 64; ++k) acc = fmaf(lane_bcast(v1, k), wc[64 + k], acc);
    h[n * DH + lane] = acc;
  }
}

// ---------------- Message precompute: msg = f16(relu(bn(h)) + eps) ----------------
__global__ __launch_bounds__(256) void k_msg(const float* __restrict__ h,
                                             const float* __restrict__ stats_in,
                                             const float* __restrict__ gamma,
                                             const float* __restrict__ beta,
                                             _Float16* __restrict__ msg) {
  int lane = threadIdx.x & 63;
  float scale = 1.f, shift = 0.f;
  if (stats_in) {
    float mu = stats_in[lane] * (1.0f / NN);
    float var = stats_in[64 + lane] * (1.0f / NN) - mu * mu;
    scale = gamma[lane] * rsqrtf(var + 1e-5f);
    shift = beta[lane] - mu * scale;
  }
  int wid = (blockIdx.x * blockDim.x + threadIdx.x) >> 6;
  int nw = (gridDim.x * blockDim.x) >> 6;
  for (int n = wid; n < NN; n += nw) {
    float r = h[n * DH + lane];
    float v = fmaxf(fmaf(r, scale, shift), 0.f) + 1e-7f;
    msg[n * DH + lane] = (_Float16)v;
  }
}

// ---------------- Fused layer: gather softmax-agg -> combine -> MFMA GEMM
//                  (+bias, +res) -> col-stats. One wave = 16 contiguous nodes.
__global__ __launch_bounds__(256) void k_layer(
    const float* __restrict__ h_pre, const _Float16* __restrict__ msg,
    const float* __restrict__ stats_in,
    const float* __restrict__ gamma, const float* __restrict__ beta,
    const int* __restrict__ row_ptr, const int* __restrict__ colb,
    const float* __restrict__ W, const float* __restrict__ b, int add_res,
    float* __restrict__ hout, float* __restrict__ stats_out) {
  __shared__ _Float16 Atile[4][1024];  // per-wave swizzled 16x64 f16 A-tile (8 KB)
  const int tid = threadIdx.x;
  const int w = tid >> 6, lane = tid & 63;
  const int gid = blockIdx.x * 4 + w;
  const int row = lane & 15, hi = lane >> 4;

  float ss0 = 0, ss1 = 0, ss2 = 0, ss3 = 0;
  float qq0 = 0, qq1 = 0, qq2 = 0, qq3 = 0;

  if (gid < NGRP) {  // wave-uniform
    float scale = 1.f, shift = 0.f;
    if (stats_in) {
      float mu = stats_in[lane] * (1.0f / NN);
      float var = stats_in[64 + lane] * (1.0f / NN) - mu * mu;
      scale = gamma[lane] * rsqrtf(var + 1e-5f);
      shift = beta[lane] - mu * scale;
    }
    // B fragments of W (64x64, row-major [k][n]) in f16:
    // lane holds k = kt*32 + hi*8 + j, n = ct*16 + row
    v8h bf[2][4];
#pragma unroll
    for (int kt = 0; kt < 2; ++kt)
#pragma unroll
      for (int ct = 0; ct < 4; ++ct)
#pragma unroll
        for (int j = 0; j < 8; ++j)
          bf[kt][ct][j] = (_Float16)W[(kt * 32 + hi * 8 + j) * DH + ct * 16 + row];

    const int base = gid * 16;
    const char* mbase = (const char*)msg + 2 * lane;
    const float* hl = h_pre + lane;
    _Float16* At = &Atile[w][0];

    for (int i = 0; i < 16; ++i) {
      int n = base + i;
      int beg = row_ptr[n], end = row_ptr[n + 1];
      float raw = hl[(size_t)n * DH];
      float s = 0.f, t = 0.f;
      for (int j = beg; j < end; j += GW) {
        int rem = end - j;  // wave-uniform
        int cc[GW];
#pragma unroll
        for (int k = 0; k < GW; ++k) cc[k] = colb[j + k];  // padded: safe
        float vv[GW];
#pragma unroll
        for (int k = 0; k < GW; ++k)
          vv[k] = (float)(*(const _Float16*)(mbase + cc[k]));
#pragma unroll
        for (int k = 0; k < GW; ++k) {
          float e = (k < rem) ? __expf(vv[k]) : 0.f;
          s += e;
          t = fmaf(e, vv[k], t);
        }
      }
      float aggv = t / (s + 1e-16f);
      float v = stats_in ? fmaxf(fmaf(raw, scale, shift), 0.f) : raw;
      v += aggv;
      // swizzled write: row i, feature lane (byte col 2*lane)
      At[(i * 128 + ((lane * 2) ^ ((i & 7) << 4))) >> 1] = (_Float16)v;
    }

    // A fragments: lane reads row=(lane&15), k = kt*32 + hi*8 + j (16B swizzle-stable)
    const int sw = (row & 7) << 4;
    v8h a0 = *(const v8h*)&At[((row * 128) + ((hi * 16) ^ sw)) >> 1];
    v8h a1 = *(const v8h*)&At[((row * 128) + ((64 + hi * 16) ^ sw)) >> 1];
    v4f c0 = {0, 0, 0, 0}, c1 = {0, 0, 0, 0}, c2 = {0, 0, 0, 0}, c3 = {0, 0, 0, 0};
    c0 = __builtin_amdgcn_mfma_f32_16x16x32_f16(a0, bf[0][0], c0, 0, 0, 0);
    c0 = __builtin_amdgcn_mfma_f32_16x16x32_f16(a1, bf[1][0], c0, 0, 0, 0);
    c1 = __builtin_amdgcn_mfma_f32_16x16x32_f16(a0, bf[0][1], c1, 0, 0, 0);
    c1 = __builtin_amdgcn_mfma_f32_16x16x32_f16(a1, bf[1][1], c1, 0, 0, 0);
    c2 = __builtin_amdgcn_mfma_f32_16x16x32_f16(a0, bf[0][2], c2, 0, 0, 0);
    c2 = __builtin_amdgcn_mfma_f32_16x16x32_f16(a1, bf[1][2], c2, 0, 0, 0);
    c3 = __builtin_amdgcn_mfma_f32_16x16x32_f16(a0, bf[0][3], c3, 0, 0, 0);
    c3 = __builtin_amdgcn_mfma_f32_16x16x32_f16(a1, bf[1][3], c3, 0, 0, 0);

    // epilogue in C layout: col = ct*16 + row, node = base + hi*4 + reg
    float b0 = b[row], b1 = b[16 + row], b2 = b[32 + row], b3 = b[48 + row];
#pragma unroll
    for (int reg = 0; reg < 4; ++reg) {
      size_t o = (size_t)(base + hi * 4 + reg) * DH;
      float a0v = c0[reg] + b0;
      float a1v = c1[reg] + b1;
      float a2v = c2[reg] + b2;
      float a3v = c3[reg] + b3;
      if (add_res) {
        a0v += h_pre[o + row];
        a1v += h_pre[o + 16 + row];
        a2v += h_pre[o + 32 + row];
        a3v += h_pre[o + 48 + row];
      }
      hout[o + row] = a0v;
      hout[o + 16 + row] = a1v;
      hout[o + 32 + row] = a2v;
      hout[o + 48 + row] = a3v;
      ss0 += a0v; qq0 = fmaf(a0v, a0v, qq0);
      ss1 += a1v; qq1 = fmaf(a1v, a1v, qq1);
      ss2 += a2v; qq2 = fmaf(a2v, a2v, qq2);
      ss3 += a3v; qq3 = fmaf(a3v, a3v, qq3);
    }
  }

  // reduce across the 4 row-groups (lanes l, l^16, l^32 share column)
#pragma unroll
  for (int off = 16; off <= 32; off <<= 1) {
    ss0 += __shfl_xor(ss0, off, 64); ss1 += __shfl_xor(ss1, off, 64);
    ss2 += __shfl_xor(ss2, off, 64); ss3 += __shfl_xor(ss3, off, 64);
    qq0 += __shfl_xor(qq0, off, 64); qq1 += __shfl_xor(qq1, off, 64);
    qq2 += __shfl_xor(qq2, off, 64); qq3 += __shfl_xor(qq3, off, 64);
  }
  __syncthreads();  // done with f16 A-tiles; reuse LDS as float scratch
  float* Sr = (float*)&Atile[0][0];
  if (lane < 16) {
    Sr[w * 128 + lane] = ss0;       Sr[w * 128 + 16 + lane] = ss1;
    Sr[w * 128 + 32 + lane] = ss2;  Sr[w * 128 + 48 + lane] = ss3;
    Sr[w * 128 + 64 + lane] = qq0;  Sr[w * 128 + 80 + lane] = qq1;
    Sr[w * 128 + 96 + lane] = qq2;  Sr[w * 128 + 112 + lane] = qq3;
  }
  __syncthreads();
  if (tid < 128) {
    float vsum = Sr[tid] + Sr[128 + tid] + Sr[256 + tid] + Sr[384 + tid];
    atomicAdd(&stats_out[tid], vsum);
  }
}

// ---------------- Final BN+ReLU + prediction head + log_softmax ----------------
__global__ __launch_bounds__(256) void k_pred(
    const float* __restrict__ h_pre, const float* __restrict__ stats_in,
    const float* __restrict__ gamma, const float* __restrict__ beta,
    const float* __restrict__ Wp, const float* __restrict__ bp,
    float* __restrict__ out) {
  int lane = threadIdx.x & 63;
  float mu = stats_in[lane] * (1.0f / NN);
  float var = stats_in[64 + lane] * (1.0f / NN) - mu * mu;
  float scale = gamma[lane] * rsqrtf(var + 1e-5f);
  float shift = beta[lane] - mu * scale;
  int lc = lane < DOUT ? lane : DOUT - 1;
  float wc[DH];
#pragma unroll
  for (int k = 0; k < DH; ++k) wc[k] = Wp[k * DOUT + lc];
  float bj = bp[lc];
  int wid = (blockIdx.x * blockDim.x + threadIdx.x) >> 6;
  int nw = (gridDim.x * blockDim.x) >> 6;
  for (int n = wid; n < NN; n += nw) {
    float raw = h_pre[n * DH + lane];
    float v = fmaxf(fmaf(raw, scale, shift), 0.f);
    float acc = bj;
#pragma unroll
    for (int k = 0; k < DH; ++k) acc = fmaf(lane_bcast(v, k), wc[k], acc);
    float xm = (lane < DOUT) ? acc : -INFINITY;
#pragma unroll
    for (int o = 32; o >= 1; o >>= 1) xm = fmaxf(xm, __shfl_xor(xm, o, 64));
    float e = (lane < DOUT) ? __expf(acc - xm) : 0.f;
#pragma unroll
    for (int o = 32; o >= 1; o >>= 1) e += __shfl_xor(e, o, 64);
    if (lane < DOUT) out[n * DOUT + lane] = acc - xm - __logf(e);
  }
}

extern "C" void kernel_launch(void* const* d_in, const int* in_sizes, int n_in,
                              void* d_out, int out_size, void* d_ws, size_t ws_size,
                              hipStream_t stream) {
  const float* x      = (const float*)d_in[0];
  const int*   ei     = (const int*)d_in[1];
  const float* W_enc  = (const float*)d_in[2];
  const float* b_enc  = (const float*)d_in[3];
  const float* Wg     = (const float*)d_in[4];
  const float* bg     = (const float*)d_in[5];
  const float* gamma  = (const float*)d_in[6];
  const float* beta   = (const float*)d_in[7];
  const float* W_pred = (const float*)d_in[8];
  const float* b_pred = (const float*)d_in[9];
  float* out = (float*)d_out;

  const int* src = ei;
  const int* dst = ei + NE;

  char* p = (char*)d_ws;
  auto alloc = [&](size_t bytes) -> void* {
    void* r = (void*)p;
    p += (bytes + 255) & ~(size_t)255;
    return r;
  };
  float*     hA      = (float*)alloc((size_t)NN * DH * 4);
  float*     hB      = (float*)alloc((size_t)NN * DH * 4);
  _Float16*  msg     = (_Float16*)alloc((size_t)NN * DH * 2);
  int*       row_ptr = (int*)alloc((size_t)(NN + 1) * 4);
  int*       cur     = (int*)alloc((size_t)NN * 4);
  int*       cnt     = (int*)alloc((size_t)NN * 4);
  int*       colb    = (int*)alloc((size_t)(NE + GW) * 4);
  int*       bsum    = (int*)alloc((size_t)NBLK * 4);
  float*     stats   = (float*)alloc((size_t)NL * 128 * 4);

  hipMemsetAsync(cnt, 0, (size_t)NN * 4, stream);
  hipMemsetAsync(stats, 0, (size_t)NL * 128 * 4, stream);
  hipMemsetAsync(colb + NE, 0, (size_t)GW * 4, stream);  // safe pad for 16-wide gather

  // ---- CSR build ----
  k_count<<<(NE + 255) / 256, 256, 0, stream>>>(dst, cnt);
  k_scan1<<<NBLK, SCAN_B, 0, stream>>>(cnt, row_ptr, bsum);
  k_scan2<<<1, 128, 0, stream>>>(bsum);
  k_scan3<<<NBLK, SCAN_B, 0, stream>>>(row_ptr, cur, bsum);
  k_scatter<<<(NE + 255) / 256, 256, 0, stream>>>(src, dst, cur, colb);

  // ---- Encoder ----
  k_encoder<<<1024, 256, 0, stream>>>(x, W_enc, b_enc, hA);

  const int MSG_BLOCKS = 1024;

  // ---- Layer 0 (no BN; combine uses raw h; msg = relu(h)+eps) ----
  k_msg<<<MSG_BLOCKS, 256, 0, stream>>>(hA, nullptr, nullptr, nullptr, msg);
  k_layer<<<LBLK, 256, 0, stream>>>(
      hA, msg, nullptr, nullptr, nullptr, row_ptr, colb, Wg, bg, 0, hB, stats);

  float* h = hB;
  float* hn = hA;
  for (int l = 1; l < NL; ++l) {
    const float* st = stats + (size_t)(l - 1) * 128;
    const float* g  = gamma + (size_t)(l - 1) * DH;
    const float* be = beta + (size_t)(l - 1) * DH;
    k_msg<<<MSG_BLOCKS, 256, 0, stream>>>(h, st, g, be, msg);
    k_layer<<<LBLK, 256, 0, stream>>>(
        h, msg, st, g, be, row_ptr, colb,
        Wg + (size_t)l * DH * DH, bg + (size_t)l * DH, 1,
        hn, stats + (size_t)l * 128);
    float* tmp = h; h = hn; hn = tmp;
  }

  // ---- Final BN + ReLU + prediction + log_softmax ----
  k_pred<<<1024, 256, 0, stream>>>(
      h, stats + (size_t)(NL - 1) * 128,
      gamma + (size_t)(NL - 1) * DH, beta + (size_t)(NL - 1) * DH,
      W_pred, b_pred, out);
}

// Round 8
// 861.906 us; speedup vs baseline: 1.9407x; 1.0591x over previous
//
#include <hip/hip_runtime.h>
#include <math.h>

#define NN 100000
#define NE 1000000
#define DH 64
#define DIN 128
#define DOUT 40
#define NL 7
#define SCAN_B 1024
#define NBLK ((NN + SCAN_B - 1) / SCAN_B)  // 98
#define GW 16              // gather width (masked); colb[] is zero-padded by GW
#define NGRP (NN / 16)     // 6250 16-node groups (exact)
#define LBLK ((NGRP + 3) / 4)

typedef _Float16 v8h __attribute__((ext_vector_type(8)));
typedef float v4f __attribute__((ext_vector_type(4)));

__device__ __forceinline__ float lane_bcast(float v, int l) {
  return __int_as_float(__builtin_amdgcn_readlane(__float_as_int(v), l));
}

// ---------------- CSR build ----------------
__global__ __launch_bounds__(256) void k_count(const int* __restrict__ dst,
                                               int* __restrict__ cnt) {
  int i = blockIdx.x * 256 + threadIdx.x;
  if (i < NE) atomicAdd(&cnt[dst[i]], 1);
}

__global__ __launch_bounds__(SCAN_B) void k_scan1(const int* __restrict__ cnt,
                                                  int* __restrict__ row_ptr,
                                                  int* __restrict__ bsum) {
  __shared__ int buf[SCAN_B];
  int i = blockIdx.x * SCAN_B + threadIdx.x;
  int v = (i < NN) ? cnt[i] : 0;
  buf[threadIdx.x] = v;
  __syncthreads();
  for (int off = 1; off < SCAN_B; off <<= 1) {
    int t = (threadIdx.x >= off) ? buf[threadIdx.x - off] : 0;
    __syncthreads();
    buf[threadIdx.x] += t;
    __syncthreads();
  }
  if (i < NN) row_ptr[i] = buf[threadIdx.x] - v;
  if (threadIdx.x == SCAN_B - 1) bsum[blockIdx.x] = buf[SCAN_B - 1];
}

__global__ __launch_bounds__(128) void k_scan2(int* __restrict__ bsum) {
  __shared__ int buf[128];
  int v = (threadIdx.x < NBLK) ? bsum[threadIdx.x] : 0;
  buf[threadIdx.x] = v;
  __syncthreads();
  for (int off = 1; off < 128; off <<= 1) {
    int t = (threadIdx.x >= off) ? buf[threadIdx.x - off] : 0;
    __syncthreads();
    buf[threadIdx.x] += t;
    __syncthreads();
  }
  if (threadIdx.x < NBLK) bsum[threadIdx.x] = buf[threadIdx.x] - v;
}

__global__ __launch_bounds__(SCAN_B) void k_scan3(int* __restrict__ row_ptr,
                                                  int* __restrict__ cur,
                                                  const int* __restrict__ bsum) {
  int i = blockIdx.x * SCAN_B + threadIdx.x;
  if (i < NN) {
    int rp = row_ptr[i] + bsum[blockIdx.x];
    row_ptr[i] = rp;
    cur[i] = rp;
  }
  if (i == 0) row_ptr[NN] = NE;
}

// colb stores BYTE offsets into the f16 msg array: src * DH * 2
__global__ __launch_bounds__(256) void k_scatter(const int* __restrict__ src,
                                                 const int* __restrict__ dst,
                                                 int* __restrict__ cur,
                                                 int* __restrict__ colb) {
  int i = blockIdx.x * 256 + threadIdx.x;
  if (i < NE) {
    int d = dst[i];
    int p = atomicAdd(&cur[d], 1);
    colb[p] = src[i] * (DH * 2);
  }
}

// ---------------- Encoder: h = x @ W_enc + b_enc ----------------
__global__ __launch_bounds__(256) void k_encoder(const float* __restrict__ x,
                                                 const float* __restrict__ W,
                                                 const float* __restrict__ b,
                                                 float* __restrict__ h) {
  int lane = threadIdx.x & 63;
  float wc[DIN];
#pragma unroll
  for (int k = 0; k < DIN; ++k) wc[k] = W[k * DH + lane];
  float bj = b[lane];
  int wid = (blockIdx.x * blockDim.x + threadIdx.x) >> 6;
  int nw = (gridDim.x * blockDim.x) >> 6;
  for (int n = wid; n < NN; n += nw) {
    float v0 = x[n * DIN + lane];
    float v1 = x[n * DIN + 64 + lane];
    float acc = bj;
#pragma unroll
    for (int k = 0; k < 64; ++k) acc = fmaf(lane_bcast(v0, k), wc[k], acc);
#pragma unroll
    for (int k = 0; k < 64; ++k) acc = fmaf(lane_bcast(v1, k), wc[64 + k], acc);
    h[n * DH + lane] = acc;
  }
}

// ---------------- Message precompute: msg = f16(relu(bn(h)) + eps) ----------------
__global__ __launch_bounds__(256) void k_msg(const float* __restrict__ h,
                                             const float* __restrict__ stats_in,
                                             const float* __restrict__ gamma,
                                             const float* __restrict__ beta,
                                             _Float16* __restrict__ msg) {
  int lane = threadIdx.x & 63;
  float scale = 1.f, shift = 0.f;
  if (stats_in) {
    float mu = stats_in[lane] * (1.0f / NN);
    float var = stats_in[64 + lane] * (1.0f / NN) - mu * mu;
    scale = gamma[lane] * rsqrtf(var + 1e-5f);
    shift = beta[lane] - mu * scale;
  }
  int wid = (blockIdx.x * blockDim.x + threadIdx.x) >> 6;
  int nw = (gridDim.x * blockDim.x) >> 6;
  for (int n = wid; n < NN; n += nw) {
    float r = h[n * DH + lane];
    float v = fmaxf(fmaf(r, scale, shift), 0.f) + 1e-7f;
    msg[n * DH + lane] = (_Float16)v;
  }
}

// ---------------- Gather + segment softmax agg: one wave per node ----------------
__global__ __launch_bounds__(256) void k_agg(const _Float16* __restrict__ msg,
                                             const int* __restrict__ row_ptr,
                                             const int* __restrict__ colb,
                                             _Float16* __restrict__ agg) {
  int lane = threadIdx.x & 63;
  int n = (blockIdx.x * 256 + threadIdx.x) >> 6;  // exact: NN*64 == 25000*256
  int beg = row_ptr[n], end = row_ptr[n + 1];
  const char* mbase = (const char*)msg + 2 * lane;
  float s = 0.f, t = 0.f;
  for (int j = beg; j < end; j += GW) {
    int rem = end - j;  // wave-uniform
    int cc[GW];
#pragma unroll
    for (int k = 0; k < GW; ++k) cc[k] = colb[j + k];  // padded: safe
    float vv[GW];
#pragma unroll
    for (int k = 0; k < GW; ++k)
      vv[k] = (float)(*(const _Float16*)(mbase + cc[k]));
#pragma unroll
    for (int k = 0; k < GW; ++k) {
      float e = (k < rem) ? __expf(vv[k]) : 0.f;
      s += e;
      t = fmaf(e, vv[k], t);
    }
  }
  agg[(size_t)n * DH + lane] = (_Float16)(t / (s + 1e-16f));
}

// ---------------- MFMA layer: combine(h,agg) -> GEMM (+bias,+res) -> col-stats
//                  One wave = 16 contiguous nodes. ----------------
__global__ __launch_bounds__(256) void k_mfma(
    const float* __restrict__ h_pre, const _Float16* __restrict__ agg,
    const float* __restrict__ stats_in,
    const float* __restrict__ gamma, const float* __restrict__ beta,
    const float* __restrict__ W, const float* __restrict__ b, int add_res,
    float* __restrict__ hout, float* __restrict__ stats_out) {
  __shared__ _Float16 Atile[4][1024];  // per-wave swizzled 16x64 f16 A-tile (8 KB)
  const int tid = threadIdx.x;
  const int w = tid >> 6, lane = tid & 63;
  const int gid = blockIdx.x * 4 + w;
  const int row = lane & 15, hi = lane >> 4;

  float ss0 = 0, ss1 = 0, ss2 = 0, ss3 = 0;
  float qq0 = 0, qq1 = 0, qq2 = 0, qq3 = 0;

  if (gid < NGRP) {  // wave-uniform
    float scale = 1.f, shift = 0.f;
    if (stats_in) {
      float mu = stats_in[lane] * (1.0f / NN);
      float var = stats_in[64 + lane] * (1.0f / NN) - mu * mu;
      scale = gamma[lane] * rsqrtf(var + 1e-5f);
      shift = beta[lane] - mu * scale;
    }
    // B fragments of W (64x64, row-major [k][n]) in f16:
    // lane holds k = kt*32 + hi*8 + j, n = ct*16 + row
    v8h bf[2][4];
#pragma unroll
    for (int kt = 0; kt < 2; ++kt)
#pragma unroll
      for (int ct = 0; ct < 4; ++ct)
#pragma unroll
        for (int j = 0; j < 8; ++j)
          bf[kt][ct][j] = (_Float16)W[(kt * 32 + hi * 8 + j) * DH + ct * 16 + row];

    const int base = gid * 16;
    const float* hl = h_pre + lane;
    const _Float16* agl = agg + lane;
    _Float16* At = &Atile[w][0];

#pragma unroll 4
    for (int i = 0; i < 16; ++i) {
      size_t o = (size_t)(base + i) * DH;
      float raw = hl[o];
      float ag = (float)agl[o];
      float v = stats_in ? fmaxf(fmaf(raw, scale, shift), 0.f) : raw;
      v += ag;
      // swizzled write: row i, feature lane (byte col 2*lane)
      At[(i * 128 + ((lane * 2) ^ ((i & 7) << 4))) >> 1] = (_Float16)v;
    }

    // A fragments: lane reads row=(lane&15), k = kt*32 + hi*8 + j (16B swizzle-stable)
    const int sw = (row & 7) << 4;
    v8h a0 = *(const v8h*)&At[((row * 128) + ((hi * 16) ^ sw)) >> 1];
    v8h a1 = *(const v8h*)&At[((row * 128) + ((64 + hi * 16) ^ sw)) >> 1];
    v4f c0 = {0, 0, 0, 0}, c1 = {0, 0, 0, 0}, c2 = {0, 0, 0, 0}, c3 = {0, 0, 0, 0};
    c0 = __builtin_amdgcn_mfma_f32_16x16x32_f16(a0, bf[0][0], c0, 0, 0, 0);
    c0 = __builtin_amdgcn_mfma_f32_16x16x32_f16(a1, bf[1][0], c0, 0, 0, 0);
    c1 = __builtin_amdgcn_mfma_f32_16x16x32_f16(a0, bf[0][1], c1, 0, 0, 0);
    c1 = __builtin_amdgcn_mfma_f32_16x16x32_f16(a1, bf[1][1], c1, 0, 0, 0);
    c2 = __builtin_amdgcn_mfma_f32_16x16x32_f16(a0, bf[0][2], c2, 0, 0, 0);
    c2 = __builtin_amdgcn_mfma_f32_16x16x32_f16(a1, bf[1][2], c2, 0, 0, 0);
    c3 = __builtin_amdgcn_mfma_f32_16x16x32_f16(a0, bf[0][3], c3, 0, 0, 0);
    c3 = __builtin_amdgcn_mfma_f32_16x16x32_f16(a1, bf[1][3], c3, 0, 0, 0);

    // epilogue in C layout: col = ct*16 + row, node = base + hi*4 + reg
    float b0 = b[row], b1 = b[16 + row], b2 = b[32 + row], b3 = b[48 + row];
#pragma unroll
    for (int reg = 0; reg < 4; ++reg) {
      size_t o = (size_t)(base + hi * 4 + reg) * DH;
      float a0v = c0[reg] + b0;
      float a1v = c1[reg] + b1;
      float a2v = c2[reg] + b2;
      float a3v = c3[reg] + b3;
      if (add_res) {
        a0v += h_pre[o + row];
        a1v += h_pre[o + 16 + row];
        a2v += h_pre[o + 32 + row];
        a3v += h_pre[o + 48 + row];
      }
      hout[o + row] = a0v;
      hout[o + 16 + row] = a1v;
      hout[o + 32 + row] = a2v;
      hout[o + 48 + row] = a3v;
      ss0 += a0v; qq0 = fmaf(a0v, a0v, qq0);
      ss1 += a1v; qq1 = fmaf(a1v, a1v, qq1);
      ss2 += a2v; qq2 = fmaf(a2v, a2v, qq2);
      ss3 += a3v; qq3 = fmaf(a3v, a3v, qq3);
    }
  }

  // reduce across the 4 row-groups (lanes l, l^16, l^32 share column)
#pragma unroll
  for (int off = 16; off <= 32; off <<= 1) {
    ss0 += __shfl_xor(ss0, off, 64); ss1 += __shfl_xor(ss1, off, 64);
    ss2 += __shfl_xor(ss2, off, 64); ss3 += __shfl_xor(ss3, off, 64);
    qq0 += __shfl_xor(qq0, off, 64); qq1 += __shfl_xor(qq1, off, 64);
    qq2 += __shfl_xor(qq2, off, 64); qq3 += __shfl_xor(qq3, off, 64);
  }
  __syncthreads();  // done with f16 A-tiles; reuse LDS as float scratch
  float* Sr = (float*)&Atile[0][0];
  if (lane < 16) {
    Sr[w * 128 + lane] = ss0;       Sr[w * 128 + 16 + lane] = ss1;
    Sr[w * 128 + 32 + lane] = ss2;  Sr[w * 128 + 48 + lane] = ss3;
    Sr[w * 128 + 64 + lane] = qq0;  Sr[w * 128 + 80 + lane] = qq1;
    Sr[w * 128 + 96 + lane] = qq2;  Sr[w * 128 + 112 + lane] = qq3;
  }
  __syncthreads();
  if (tid < 128) {
    float vsum = Sr[tid] + Sr[128 + tid] + Sr[256 + tid] + Sr[384 + tid];
    atomicAdd(&stats_out[tid], vsum);
  }
}

// ---------------- Final BN+ReLU + prediction head + log_softmax ----------------
__global__ __launch_bounds__(256) void k_pred(
    const float* __restrict__ h_pre, const float* __restrict__ stats_in,
    const float* __restrict__ gamma, const float* __restrict__ beta,
    const float* __restrict__ Wp, const float* __restrict__ bp,
    float* __restrict__ out) {
  int lane = threadIdx.x & 63;
  float mu = stats_in[lane] * (1.0f / NN);
  float var = stats_in[64 + lane] * (1.0f / NN) - mu * mu;
  float scale = gamma[lane] * rsqrtf(var + 1e-5f);
  float shift = beta[lane] - mu * scale;
  int lc = lane < DOUT ? lane : DOUT - 1;
  float wc[DH];
#pragma unroll
  for (int k = 0; k < DH; ++k) wc[k] = Wp[k * DOUT + lc];
  float bj = bp[lc];
  int wid = (blockIdx.x * blockDim.x + threadIdx.x) >> 6;
  int nw = (gridDim.x * blockDim.x) >> 6;
  for (int n = wid; n < NN; n += nw) {
    float raw = h_pre[n * DH + lane];
    float v = fmaxf(fmaf(raw, scale, shift), 0.f);
    float acc = bj;
#pragma unroll
    for (int k = 0; k < DH; ++k) acc = fmaf(lane_bcast(v, k), wc[k], acc);
    float xm = (lane < DOUT) ? acc : -INFINITY;
#pragma unroll
    for (int o = 32; o >= 1; o >>= 1) xm = fmaxf(xm, __shfl_xor(xm, o, 64));
    float e = (lane < DOUT) ? __expf(acc - xm) : 0.f;
#pragma unroll
    for (int o = 32; o >= 1; o >>= 1) e += __shfl_xor(e, o, 64);
    if (lane < DOUT) out[n * DOUT + lane] = acc - xm - __logf(e);
  }
}

extern "C" void kernel_launch(void* const* d_in, const int* in_sizes, int n_in,
                              void* d_out, int out_size, void* d_ws, size_t ws_size,
                              hipStream_t stream) {
  const float* x      = (const float*)d_in[0];
  const int*   ei     = (const int*)d_in[1];
  const float* W_enc  = (const float*)d_in[2];
  const float* b_enc  = (const float*)d_in[3];
  const float* Wg     = (const float*)d_in[4];
  const float* bg     = (const float*)d_in[5];
  const float* gamma  = (const float*)d_in[6];
  const float* beta   = (const float*)d_in[7];
  const float* W_pred = (const float*)d_in[8];
  const float* b_pred = (const float*)d_in[9];
  float* out = (float*)d_out;

  const int* src = ei;
  const int* dst = ei + NE;

  char* p = (char*)d_ws;
  auto alloc = [&](size_t bytes) -> void* {
    void* r = (void*)p;
    p += (bytes + 255) & ~(size_t)255;
    return r;
  };
  float*     hA      = (float*)alloc((size_t)NN * DH * 4);
  float*     hB      = (float*)alloc((size_t)NN * DH * 4);
  _Float16*  msg     = (_Float16*)alloc((size_t)NN * DH * 2);
  _Float16*  agg     = (_Float16*)alloc((size_t)NN * DH * 2);
  int*       row_ptr = (int*)alloc((size_t)(NN + 1) * 4);
  int*       cur     = (int*)alloc((size_t)NN * 4);
  int*       cnt     = (int*)alloc((size_t)NN * 4);
  int*       colb    = (int*)alloc((size_t)(NE + GW) * 4);
  int*       bsum    = (int*)alloc((size_t)NBLK * 4);
  float*     stats   = (float*)alloc((size_t)NL * 128 * 4);

  hipMemsetAsync(cnt, 0, (size_t)NN * 4, stream);
  hipMemsetAsync(stats, 0, (size_t)NL * 128 * 4, stream);
  hipMemsetAsync(colb + NE, 0, (size_t)GW * 4, stream);  // safe pad for 16-wide gather

  // ---- CSR build ----
  k_count<<<(NE + 255) / 256, 256, 0, stream>>>(dst, cnt);
  k_scan1<<<NBLK, SCAN_B, 0, stream>>>(cnt, row_ptr, bsum);
  k_scan2<<<1, 128, 0, stream>>>(bsum);
  k_scan3<<<NBLK, SCAN_B, 0, stream>>>(row_ptr, cur, bsum);
  k_scatter<<<(NE + 255) / 256, 256, 0, stream>>>(src, dst, cur, colb);

  // ---- Encoder ----
  k_encoder<<<1024, 256, 0, stream>>>(x, W_enc, b_enc, hA);

  const int MSG_BLOCKS = 1024;
  const int AGG_BLOCKS = NN * 64 / 256;  // one wave per node

  // ---- Layer 0 (no BN; combine uses raw h; msg = relu(h)+eps) ----
  k_msg<<<MSG_BLOCKS, 256, 0, stream>>>(hA, nullptr, nullptr, nullptr, msg);
  k_agg<<<AGG_BLOCKS, 256, 0, stream>>>(msg, row_ptr, colb, agg);
  k_mfma<<<LBLK, 256, 0, stream>>>(
      hA, agg, nullptr, nullptr, nullptr, Wg, bg, 0, hB, stats);

  float* h = hB;
  float* hn = hA;
  for (int l = 1; l < NL; ++l) {
    const float* st = stats + (size_t)(l - 1) * 128;
    const float* g  = gamma + (size_t)(l - 1) * DH;
    const float* be = beta + (size_t)(l - 1) * DH;
    k_msg<<<MSG_BLOCKS, 256, 0, stream>>>(h, st, g, be, msg);
    k_agg<<<AGG_BLOCKS, 256, 0, stream>>>(msg, row_ptr, colb, agg);
    k_mfma<<<LBLK, 256, 0, stream>>>(
        h, agg, st, g, be,
        Wg + (size_t)l * DH * DH, bg + (size_t)l * DH, 1,
        hn, stats + (size_t)l * 128);
    float* tmp = h; h = hn; hn = tmp;
  }

  // ---- Final BN + ReLU + prediction + log_softmax ----
  k_pred<<<1024, 256, 0, stream>>>(
      h, stats + (size_t)(NL - 1) * 128,
      gamma + (size_t)(NL - 1) * DH, beta + (size_t)(NL - 1) * DH,
      W_pred, b_pred, out);
}